// Round 6
// baseline (455.100 us; speedup 1.0000x reference)
//
#include <hip/hip_runtime.h>

// Problem constants: B=8, H=8, L=1024, DK=64
constexpr int SL = 1024;   // sequence length
constexpr int NBH = 64;    // B*H rows

// Workspace layout (float offsets)
constexpr int QP_OFF = 0;         // Qp [64][1024]
constexpr int KP_OFF = 65536;     // Kp [64][1024]
constexpr int Y_OFF  = 131072;    // conv outputs, 4 branches x [64][1024]
constexpr int QM_OFF = 655360;    // Qm [64][1024]
constexpr int KM_OFF = 720896;    // Km [64][1024]
constexpr int ST_OFF = 786432;    // BN stats [4][8][2] = 64 floats (atomic accum)
constexpr int C_OFF  = 786496;    // scalar c = dot(wbq,wbk)/8
constexpr int VT_OFF = 786560;    // V packed bf16 B-fragments: 4.19M ushort = 8.4 MB

typedef __attribute__((ext_vector_type(8))) short short8;
typedef __attribute__((ext_vector_type(4))) float f32x4;

__device__ inline unsigned short f2bf(float x) {
    unsigned int u = __float_as_uint(x);
    unsigned int r = (u + 0x7fff + ((u >> 16) & 1)) >> 16;  // RNE
    return (unsigned short)r;
}

// ---------------- K1: proj (Qp,Kp) + c + V bf16 B-fragment pack, fused ----
// blocks [0,8192): projections, 16 rows/block (16 lanes per row, float4/lane)
// blocks [8192,10240): vpack  |  block 10240: scalar c
__global__ __launch_bounds__(256) void k_projpack(
    const float* __restrict__ Q, const float* __restrict__ K,
    const float* __restrict__ V,
    const float* __restrict__ wq, const float* __restrict__ wk,
    const float* __restrict__ wbq, const float* __restrict__ wbk,
    float* __restrict__ ws)
{
    int b = blockIdx.x;
    int tid = threadIdx.x;
    if (b < 8192) {
        bool isQ = b < 4096;
        const float* src = isQ ? Q : K;
        const float* w   = isQ ? wq : wk;
        int row = (b - (isQ ? 0 : 4096)) * 16 + (tid >> 4);
        int l16 = tid & 15;
        float4 x  = ((const float4*)(src + row * 64))[l16];
        float4 w4 = ((const float4*)w)[l16];
        float v = x.x * w4.x + x.y * w4.y + x.z * w4.z + x.w * w4.w;
        #pragma unroll
        for (int m = 8; m; m >>= 1) v += __shfl_xor(v, m);
        if (l16 == 0) ws[(isQ ? QP_OFF : KP_OFF) + row] = v;
    } else if (b < 10240) {
        // V pack: [bh][chunk4][dsub4][kstep8][lane64][j8]
        int t = (b - 8192) * 256 + tid;    // 524288 total
        int lane = t & 63;
        int s    = (t >> 6) & 7;
        int dsub = (t >> 9) & 3;
        int chunk= (t >> 11) & 3;
        int bh   = t >> 13;
        const float* vb = V + bh * (SL * 64);
        int k0 = chunk * 256 + s * 32 + (lane >> 4) * 8;
        int d  = dsub * 16 + (lane & 15);
        unsigned short o[8];
        #pragma unroll
        for (int j = 0; j < 8; j++) o[j] = f2bf(vb[(k0 + j) * 64 + d]);
        unsigned short* vt = (unsigned short*)(ws + VT_OFF);
        *(short8*)(vt + (size_t)t * 8) = *(short8*)o;
    } else {
        if (tid < 64) {
            float v = wbq[tid] * wbk[tid];
            #pragma unroll
            for (int m = 32; m; m >>= 1) v += __shfl_xor(v, m);
            if (tid == 0) ws[C_OFF] = v * 0.125f;  // / sqrt(64)
        }
    }
}

// ---------------- K2: conv1d + bias, accumulate BN stats ----------------
// grid: 256 blocks = branch(4) x batch n(8) x seg(8). Each: 8 ch x 128 pos.
__global__ __launch_bounds__(256) void k_conv(
    float* __restrict__ ws,
    const float* __restrict__ w0, const float* __restrict__ b0,
    const float* __restrict__ w1, const float* __restrict__ b1,
    const float* __restrict__ w2, const float* __restrict__ b2,
    const float* __restrict__ w3, const float* __restrict__ b3)
{
    int branch = blockIdx.x >> 6;
    int n = (blockIdx.x >> 3) & 7;
    int seg = blockIdx.x & 7;
    int t0 = seg * 128;
    const float* wp = branch == 0 ? w0 : branch == 1 ? w1 : branch == 2 ? w2 : w3;
    const float* bp = branch == 0 ? b0 : branch == 1 ? b1 : branch == 2 ? b2 : b3;
    const int F = (branch & 1) ? 9 : 3;
    const int PAD = F >> 1;
    const float* x = ws + ((branch < 2) ? QP_OFF : KP_OFF) + n * 8 * SL;

    __shared__ float xl[8][136];    // 128 + halo 4 each side (offset +4)
    __shared__ float wl[8 * 8 * 9];
    __shared__ float bl[8];
    int tid = threadIdx.x;
    for (int i = tid; i < 8 * 8 * F; i += 256) wl[i] = wp[i];
    if (tid < 8) bl[tid] = bp[tid];
    for (int i = tid; i < 8 * 136; i += 256) {
        int ci = i / 136; int tt = i - ci * 136;
        int ta = t0 + tt - 4;
        xl[ci][tt] = (ta >= 0 && ta < SL) ? x[ci * SL + ta] : 0.f;
    }
    __syncthreads();
    int c = tid >> 5, u = tid & 31;
    float s1 = 0.f, s2 = 0.f;
    float* yout = ws + Y_OFF + branch * (NBH * SL) + (n * 8 + c) * SL + t0;
    float res[4];
    #pragma unroll
    for (int q = 0; q < 4; q++) {
        int tl = u * 4 + q;
        float acc = bl[c];
        for (int ci = 0; ci < 8; ci++) {
            const float* xr = &xl[ci][tl + 4 - PAD];
            const float* wr = &wl[(c * 8 + ci) * F];
            for (int f = 0; f < F; f++) acc += wr[f] * xr[f];
        }
        res[q] = acc;
        s1 += acc; s2 += acc * acc;
    }
    *(float4*)&yout[u * 4] = make_float4(res[0], res[1], res[2], res[3]);
    #pragma unroll
    for (int m = 16; m; m >>= 1) {
        s1 += __shfl_xor(s1, m);
        s2 += __shfl_xor(s2, m);
    }
    if (u == 0) {
        atomicAdd(&ws[ST_OFF + (branch * 8 + c) * 2],     s1);
        atomicAdd(&ws[ST_OFF + (branch * 8 + c) * 2 + 1], s2);
    }
}

// ---------------- K3: fused BN(train) + softmax + concat-scramble max ------
// 128 blocks = which(2) x i(8) x j(8). Each block: BN+softmax of the two
// source rows (channels c0=2(j&3), c0+1 of branch which*2+(n>=8), n-row n&7),
// then Qm/Km row = [pairwise-max(row c0) | pairwise-max(row c0+1)].
__global__ __launch_bounds__(256) void k_bnmix(
    float* __restrict__ ws,
    const float* __restrict__ g0, const float* __restrict__ be0,
    const float* __restrict__ g1, const float* __restrict__ be1,
    const float* __restrict__ g2, const float* __restrict__ be2,
    const float* __restrict__ g3, const float* __restrict__ be3)
{
    int blk = blockIdx.x;
    int which = blk >> 6;
    int i = (blk >> 3) & 7, j = blk & 7;
    int n = 2 * i + (j >= 4 ? 1 : 0);
    int br = which * 2 + (n >= 8 ? 1 : 0);
    int row = n & 7;
    int tid = threadIdx.x;
    int half = tid >> 7;               // 0 -> channel c0, 1 -> c0+1
    int u = tid & 127;
    int c = 2 * (j & 3) + half;
    const float* gp = br == 0 ? g0 : br == 1 ? g1 : br == 2 ? g2 : g3;
    const float* bp = br == 0 ? be0 : br == 1 ? be1 : br == 2 ? be2 : be3;
    float s1 = ws[ST_OFF + (br * 8 + c) * 2];
    float s2 = ws[ST_OFF + (br * 8 + c) * 2 + 1];
    float mu  = s1 * (1.f / 8192.f);
    float var = s2 * (1.f / 8192.f) - mu * mu;   // biased var over (B, L)
    float sc = gp[c] * rsqrtf(var + 1e-5f);
    float sh = bp[c] - mu * sc;
    const float* y = ws + Y_OFF + br * (NBH * SL) + (row * 8 + c) * SL;
    float4 ya = ((const float4*)y)[u * 2];
    float4 yb = ((const float4*)y)[u * 2 + 1];
    float z[8] = { ya.x * sc + sh, ya.y * sc + sh, ya.z * sc + sh, ya.w * sc + sh,
                   yb.x * sc + sh, yb.y * sc + sh, yb.z * sc + sh, yb.w * sc + sh };
    float mx = z[0];
    #pragma unroll
    for (int q = 1; q < 8; q++) mx = fmaxf(mx, z[q]);
    __shared__ float r1[4], r2[4];
    #pragma unroll
    for (int m = 32; m; m >>= 1) mx = fmaxf(mx, __shfl_xor(mx, m));
    if ((tid & 63) == 0) r1[tid >> 6] = mx;
    __syncthreads();
    mx = half ? fmaxf(r1[2], r1[3]) : fmaxf(r1[0], r1[1]);
    float e[8];
    float s = 0.f;
    #pragma unroll
    for (int q = 0; q < 8; q++) { e[q] = __expf(z[q] - mx); s += e[q]; }
    #pragma unroll
    for (int m = 32; m; m >>= 1) s += __shfl_xor(s, m);
    if ((tid & 63) == 0) r2[tid >> 6] = s;
    __syncthreads();
    s = half ? (r2[2] + r2[3]) : (r2[0] + r2[1]);
    float inv = 1.f / s;
    float4 o = make_float4(fmaxf(e[0], e[1]) * inv, fmaxf(e[2], e[3]) * inv,
                           fmaxf(e[4], e[5]) * inv, fmaxf(e[6], e[7]) * inv);
    float* outp = ws + (which ? KM_OFF : QM_OFF) + i * 8192 + j * 1024 + half * 512;
    ((float4*)outp)[u] = o;
}

// ---------------- K4: fused rank-1 attn softmax + attn write + MFMA PV ----
// grid: 1024 blocks = bh(64) x q-tile(16 of 64 rows). 256 threads = 4 waves.
// Round-5 structure (LDS-staged V fragments) + SINGLE CHANGE: nontemporal
// attn stores (268 MB streaming writes bypass L2 -> VT table stays resident).
__global__ __launch_bounds__(256) void k_attn(
    float* __restrict__ out, const float* __restrict__ ws)
{
    int bh = blockIdx.x >> 4;
    int qt = blockIdx.x & 15;
    int tid = threadIdx.x;
    __shared__ float kml[1024];
    __shared__ float aq[64], mq[64], rq[64];
    __shared__ unsigned short bpk[4 * 8 * 64 * 8];   // 32 KB B-fragment chunk
    __shared__ float red[256];
    __shared__ float rmx[4], rmn[4];

    const float* km = ws + KM_OFF + bh * SL;
    const float* qm = ws + QM_OFF + bh * SL + qt * 64;
    float c = ws[C_OFF];

    // load Km; block max/min (logits monotone in Km -> exact max subtraction)
    float lmax = -1e30f, lmin = 1e30f;
    #pragma unroll
    for (int i = 0; i < 4; i++) {
        float v = km[tid + 256 * i];
        kml[tid + 256 * i] = v;
        lmax = fmaxf(lmax, v); lmin = fminf(lmin, v);
    }
    #pragma unroll
    for (int m = 32; m; m >>= 1) {
        lmax = fmaxf(lmax, __shfl_xor(lmax, m));
        lmin = fminf(lmin, __shfl_xor(lmin, m));
    }
    if ((tid & 63) == 0) { rmx[tid >> 6] = lmax; rmn[tid >> 6] = lmin; }
    __syncthreads();
    float kmax = fmaxf(fmaxf(rmx[0], rmx[1]), fmaxf(rmx[2], rmx[3]));
    float kmin = fminf(fminf(rmn[0], rmn[1]), fminf(rmn[2], rmn[3]));
    if (tid < 64) {
        float a = c * qm[tid];
        aq[tid] = a;
        mq[tid] = (a > 0.f) ? a * kmax : a * kmin;
    }
    __syncthreads();
    // denominators: 4 threads per q row, 256 k each
    {
        int q = tid >> 2, g = tid & 3;
        float a = aq[q], m = mq[q];
        float s = 0.f;
        const float* kp = kml + g * 256;
        for (int k = 0; k < 256; k++) s += __expf(a * kp[k] - m);
        red[tid] = s;
        __syncthreads();
        if (tid < 64) {
            float d = red[tid * 4] + red[tid * 4 + 1] + red[tid * 4 + 2] + red[tid * 4 + 3];
            rq[tid] = 1.f / d;
        }
        __syncthreads();
    }

    int w = tid >> 6, lane = tid & 63;
    int m16 = lane & 15, kg = lane >> 4;
    int qloc = w * 16 + m16;                      // this lane's q row (A-frag m)
    float a = aq[qloc], mm = mq[qloc], rr = rq[qloc];
    float* attn_row = out + 4194304 + ((size_t)(bh * SL + qt * 64 + qloc)) * SL;
    const uint4* vt4 = (const uint4*)((const unsigned short*)(ws + VT_OFF) + (size_t)bh * 4 * 16384);

    f32x4 acc0 = {0,0,0,0}, acc1 = {0,0,0,0}, acc2 = {0,0,0,0}, acc3 = {0,0,0,0};

    for (int ch = 0; ch < 4; ch++) {
        // stage 32 KB of packed V-fragments (linear, conflict-free)
        const uint4* src = vt4 + ch * 2048;
        uint4* dst = (uint4*)bpk;
        #pragma unroll
        for (int i = 0; i < 8; i++) dst[tid + 256 * i] = src[tid + 256 * i];
        __syncthreads();

        #pragma unroll
        for (int s = 0; s < 8; s++) {
            int k0 = ch * 256 + s * 32 + kg * 8;
            const float* kp = kml + k0;
            float e[8];
            #pragma unroll
            for (int j = 0; j < 8; j++) e[j] = __expf(a * kp[j] - mm) * rr;
            // write attn (fp32, exact), nontemporal: 2x 16B
            f32x4 e0123 = { e[0], e[1], e[2], e[3] };
            f32x4 e4567 = { e[4], e[5], e[6], e[7] };
            __builtin_nontemporal_store(e0123, (f32x4*)(attn_row + k0));
            __builtin_nontemporal_store(e4567, (f32x4*)(attn_row + k0 + 4));
            // A fragment in bf16 (lane computes exactly its own fragment)
            unsigned short af[8];
            #pragma unroll
            for (int j = 0; j < 8; j++) af[j] = f2bf(e[j]);
            short8 av = *(short8*)af;
            const short8* bbase = (const short8*)bpk + s * 64 + lane;
            short8 b0 = bbase[0 * 512];
            short8 b1 = bbase[1 * 512];
            short8 b2 = bbase[2 * 512];
            short8 b3 = bbase[3 * 512];
            acc0 = __builtin_amdgcn_mfma_f32_16x16x32_bf16(av, b0, acc0, 0, 0, 0);
            acc1 = __builtin_amdgcn_mfma_f32_16x16x32_bf16(av, b1, acc1, 0, 0, 0);
            acc2 = __builtin_amdgcn_mfma_f32_16x16x32_bf16(av, b2, acc2, 0, 0, 0);
            acc3 = __builtin_amdgcn_mfma_f32_16x16x32_bf16(av, b3, acc3, 0, 0, 0);
        }
        __syncthreads();
    }
    // epilogue: C layout col=lane&15 (d), row=(lane>>4)*4+reg (q)
    float* ctx = out + ((size_t)(bh * SL + qt * 64 + w * 16)) * 64;
    #pragma unroll
    for (int reg = 0; reg < 4; reg++) {
        int row = kg * 4 + reg;
        float* cp = ctx + row * 64 + m16;
        cp[0]  = acc0[reg];
        cp[16] = acc1[reg];
        cp[32] = acc2[reg];
        cp[48] = acc3[reg];
    }
}

extern "C" void kernel_launch(void* const* d_in, const int* in_sizes, int n_in,
                              void* d_out, int out_size, void* d_ws, size_t ws_size,
                              hipStream_t stream)
{
    const float* Q      = (const float*)d_in[0];
    const float* K      = (const float*)d_in[1];
    const float* V      = (const float*)d_in[2];
    const float* wq     = (const float*)d_in[4];
    const float* wk     = (const float*)d_in[5];
    const float* wbq    = (const float*)d_in[6];
    const float* wbk    = (const float*)d_in[7];
    const float* cq3_w  = (const float*)d_in[8];
    const float* cq3_b  = (const float*)d_in[9];
    const float* cq9_w  = (const float*)d_in[10];
    const float* cq9_b  = (const float*)d_in[11];
    const float* ck3_w  = (const float*)d_in[12];
    const float* ck3_b  = (const float*)d_in[13];
    const float* ck9_w  = (const float*)d_in[14];
    const float* ck9_b  = (const float*)d_in[15];
    const float* bnq3_g = (const float*)d_in[16];
    const float* bnq3_b = (const float*)d_in[17];
    const float* bnq9_g = (const float*)d_in[18];
    const float* bnq9_b = (const float*)d_in[19];
    const float* bnk3_g = (const float*)d_in[20];
    const float* bnk3_b = (const float*)d_in[21];
    const float* bnk9_g = (const float*)d_in[22];
    const float* bnk9_b = (const float*)d_in[23];
    float* out = (float*)d_out;
    float* ws  = (float*)d_ws;

    (void)hipMemsetAsync(ws + ST_OFF, 0, 64 * sizeof(float), stream);

    k_projpack<<<10241, 256, 0, stream>>>(Q, K, V, wq, wk, wbq, wbk, ws);
    k_conv<<<256, 256, 0, stream>>>(ws, cq3_w, cq3_b, cq9_w, cq9_b,
                                    ck3_w, ck3_b, ck9_w, ck9_b);
    k_bnmix<<<128, 256, 0, stream>>>(ws, bnq3_g, bnq3_b, bnq9_g, bnq9_b,
                                     bnk3_g, bnk3_b, bnk9_g, bnk9_b);
    k_attn<<<1024, 256, 0, stream>>>(out, ws);
}

// Round 7
// 409.064 us; speedup vs baseline: 1.1125x; 1.1125x over previous
//
#include <hip/hip_runtime.h>

// Problem constants: B=8, H=8, L=1024, DK=64
constexpr int SL = 1024;   // sequence length
constexpr int NBH = 64;    // B*H rows

// Workspace layout (float offsets)
constexpr int QP_OFF = 0;         // Qp [64][1024]
constexpr int KP_OFF = 65536;     // Kp [64][1024]
constexpr int Y_OFF  = 131072;    // conv outputs, 4 branches x [64][1024]
constexpr int QM_OFF = 655360;    // Qm [64][1024]
constexpr int KM_OFF = 720896;    // Km [64][1024]
constexpr int ST_OFF = 786432;    // BN stats [4][8][2] = 64 floats (atomic accum)
constexpr int C_OFF  = 786496;    // scalar c = dot(wbq,wbk)/8
constexpr int VT_OFF = 786560;    // V packed bf16 B-fragments: 4.19M ushort = 8.4 MB

typedef __attribute__((ext_vector_type(8))) short short8;
typedef __attribute__((ext_vector_type(4))) float f32x4;

__device__ inline unsigned short f2bf(float x) {
    unsigned int u = __float_as_uint(x);
    unsigned int r = (u + 0x7fff + ((u >> 16) & 1)) >> 16;  // RNE
    return (unsigned short)r;
}

// ---------------- K1: proj (Qp,Kp) + c + V bf16 B-fragment pack, fused ----
// blocks [0,8192): projections, 16 rows/block (16 lanes per row, float4/lane)
// blocks [8192,10240): vpack  |  block 10240: scalar c
__global__ __launch_bounds__(256) void k_projpack(
    const float* __restrict__ Q, const float* __restrict__ K,
    const float* __restrict__ V,
    const float* __restrict__ wq, const float* __restrict__ wk,
    const float* __restrict__ wbq, const float* __restrict__ wbk,
    float* __restrict__ ws)
{
    int b = blockIdx.x;
    int tid = threadIdx.x;
    if (b < 8192) {
        bool isQ = b < 4096;
        const float* src = isQ ? Q : K;
        const float* w   = isQ ? wq : wk;
        int row = (b - (isQ ? 0 : 4096)) * 16 + (tid >> 4);
        int l16 = tid & 15;
        float4 x  = ((const float4*)(src + row * 64))[l16];
        float4 w4 = ((const float4*)w)[l16];
        float v = x.x * w4.x + x.y * w4.y + x.z * w4.z + x.w * w4.w;
        #pragma unroll
        for (int m = 8; m; m >>= 1) v += __shfl_xor(v, m);
        if (l16 == 0) ws[(isQ ? QP_OFF : KP_OFF) + row] = v;
    } else if (b < 10240) {
        // V pack: [bh][chunk4][dsub4][kstep8][lane64][j8]
        int t = (b - 8192) * 256 + tid;    // 524288 total
        int lane = t & 63;
        int s    = (t >> 6) & 7;
        int dsub = (t >> 9) & 3;
        int chunk= (t >> 11) & 3;
        int bh   = t >> 13;
        const float* vb = V + bh * (SL * 64);
        int k0 = chunk * 256 + s * 32 + (lane >> 4) * 8;
        int d  = dsub * 16 + (lane & 15);
        unsigned short o[8];
        #pragma unroll
        for (int j = 0; j < 8; j++) o[j] = f2bf(vb[(k0 + j) * 64 + d]);
        unsigned short* vt = (unsigned short*)(ws + VT_OFF);
        *(short8*)(vt + (size_t)t * 8) = *(short8*)o;
    } else {
        if (tid < 64) {
            float v = wbq[tid] * wbk[tid];
            #pragma unroll
            for (int m = 32; m; m >>= 1) v += __shfl_xor(v, m);
            if (tid == 0) ws[C_OFF] = v * 0.125f;  // / sqrt(64)
        }
    }
}

// ---------------- K2: conv1d + bias, accumulate BN stats ----------------
// grid: 256 blocks = branch(4) x batch n(8) x seg(8). Each: 8 ch x 128 pos.
__global__ __launch_bounds__(256) void k_conv(
    float* __restrict__ ws,
    const float* __restrict__ w0, const float* __restrict__ b0,
    const float* __restrict__ w1, const float* __restrict__ b1,
    const float* __restrict__ w2, const float* __restrict__ b2,
    const float* __restrict__ w3, const float* __restrict__ b3)
{
    int branch = blockIdx.x >> 6;
    int n = (blockIdx.x >> 3) & 7;
    int seg = blockIdx.x & 7;
    int t0 = seg * 128;
    const float* wp = branch == 0 ? w0 : branch == 1 ? w1 : branch == 2 ? w2 : w3;
    const float* bp = branch == 0 ? b0 : branch == 1 ? b1 : branch == 2 ? b2 : b3;
    const int F = (branch & 1) ? 9 : 3;
    const int PAD = F >> 1;
    const float* x = ws + ((branch < 2) ? QP_OFF : KP_OFF) + n * 8 * SL;

    __shared__ float xl[8][136];    // 128 + halo 4 each side (offset +4)
    __shared__ float wl[8 * 8 * 9];
    __shared__ float bl[8];
    int tid = threadIdx.x;
    for (int i = tid; i < 8 * 8 * F; i += 256) wl[i] = wp[i];
    if (tid < 8) bl[tid] = bp[tid];
    for (int i = tid; i < 8 * 136; i += 256) {
        int ci = i / 136; int tt = i - ci * 136;
        int ta = t0 + tt - 4;
        xl[ci][tt] = (ta >= 0 && ta < SL) ? x[ci * SL + ta] : 0.f;
    }
    __syncthreads();
    int c = tid >> 5, u = tid & 31;
    float s1 = 0.f, s2 = 0.f;
    float* yout = ws + Y_OFF + branch * (NBH * SL) + (n * 8 + c) * SL + t0;
    float res[4];
    #pragma unroll
    for (int q = 0; q < 4; q++) {
        int tl = u * 4 + q;
        float acc = bl[c];
        for (int ci = 0; ci < 8; ci++) {
            const float* xr = &xl[ci][tl + 4 - PAD];
            const float* wr = &wl[(c * 8 + ci) * F];
            for (int f = 0; f < F; f++) acc += wr[f] * xr[f];
        }
        res[q] = acc;
        s1 += acc; s2 += acc * acc;
    }
    *(float4*)&yout[u * 4] = make_float4(res[0], res[1], res[2], res[3]);
    #pragma unroll
    for (int m = 16; m; m >>= 1) {
        s1 += __shfl_xor(s1, m);
        s2 += __shfl_xor(s2, m);
    }
    if (u == 0) {
        atomicAdd(&ws[ST_OFF + (branch * 8 + c) * 2],     s1);
        atomicAdd(&ws[ST_OFF + (branch * 8 + c) * 2 + 1], s2);
    }
}

// ---------------- K3: fused BN(train) + softmax + concat-scramble max ------
// 128 blocks = which(2) x i(8) x j(8). Each block: BN+softmax of the two
// source rows (channels c0=2(j&3), c0+1 of branch which*2+(n>=8), n-row n&7),
// then Qm/Km row = [pairwise-max(row c0) | pairwise-max(row c0+1)].
__global__ __launch_bounds__(256) void k_bnmix(
    float* __restrict__ ws,
    const float* __restrict__ g0, const float* __restrict__ be0,
    const float* __restrict__ g1, const float* __restrict__ be1,
    const float* __restrict__ g2, const float* __restrict__ be2,
    const float* __restrict__ g3, const float* __restrict__ be3)
{
    int blk = blockIdx.x;
    int which = blk >> 6;
    int i = (blk >> 3) & 7, j = blk & 7;
    int n = 2 * i + (j >= 4 ? 1 : 0);
    int br = which * 2 + (n >= 8 ? 1 : 0);
    int row = n & 7;
    int tid = threadIdx.x;
    int half = tid >> 7;               // 0 -> channel c0, 1 -> c0+1
    int u = tid & 127;
    int c = 2 * (j & 3) + half;
    const float* gp = br == 0 ? g0 : br == 1 ? g1 : br == 2 ? g2 : g3;
    const float* bp = br == 0 ? be0 : br == 1 ? be1 : br == 2 ? be2 : be3;
    float s1 = ws[ST_OFF + (br * 8 + c) * 2];
    float s2 = ws[ST_OFF + (br * 8 + c) * 2 + 1];
    float mu  = s1 * (1.f / 8192.f);
    float var = s2 * (1.f / 8192.f) - mu * mu;   // biased var over (B, L)
    float sc = gp[c] * rsqrtf(var + 1e-5f);
    float sh = bp[c] - mu * sc;
    const float* y = ws + Y_OFF + br * (NBH * SL) + (row * 8 + c) * SL;
    float4 ya = ((const float4*)y)[u * 2];
    float4 yb = ((const float4*)y)[u * 2 + 1];
    float z[8] = { ya.x * sc + sh, ya.y * sc + sh, ya.z * sc + sh, ya.w * sc + sh,
                   yb.x * sc + sh, yb.y * sc + sh, yb.z * sc + sh, yb.w * sc + sh };
    float mx = z[0];
    #pragma unroll
    for (int q = 1; q < 8; q++) mx = fmaxf(mx, z[q]);
    __shared__ float r1[4], r2[4];
    #pragma unroll
    for (int m = 32; m; m >>= 1) mx = fmaxf(mx, __shfl_xor(mx, m));
    if ((tid & 63) == 0) r1[tid >> 6] = mx;
    __syncthreads();
    mx = half ? fmaxf(r1[2], r1[3]) : fmaxf(r1[0], r1[1]);
    float e[8];
    float s = 0.f;
    #pragma unroll
    for (int q = 0; q < 8; q++) { e[q] = __expf(z[q] - mx); s += e[q]; }
    #pragma unroll
    for (int m = 32; m; m >>= 1) s += __shfl_xor(s, m);
    if ((tid & 63) == 0) r2[tid >> 6] = s;
    __syncthreads();
    s = half ? (r2[2] + r2[3]) : (r2[0] + r2[1]);
    float inv = 1.f / s;
    float4 o = make_float4(fmaxf(e[0], e[1]) * inv, fmaxf(e[2], e[3]) * inv,
                           fmaxf(e[4], e[5]) * inv, fmaxf(e[6], e[7]) * inv);
    float* outp = ws + (which ? KM_OFF : QM_OFF) + i * 8192 + j * 1024 + half * 512;
    ((float4*)outp)[u] = o;
}

// ---------------- K4: fused rank-1 attn softmax + attn write + MFMA PV ----
// grid: 1024 blocks = bh(64) x q-tile(16 of 64 rows). 256 threads = 4 waves.
// Measured-best structure (round 5, 410.8 us total): LDS-staged V fragments
// via ds_read_b128; REGULAR stores (NT stores cost +44 us on gfx950 — R6).
__global__ __launch_bounds__(256) void k_attn(
    float* __restrict__ out, const float* __restrict__ ws)
{
    int bh = blockIdx.x >> 4;
    int qt = blockIdx.x & 15;
    int tid = threadIdx.x;
    __shared__ float kml[1024];
    __shared__ float aq[64], mq[64], rq[64];
    __shared__ unsigned short bpk[4 * 8 * 64 * 8];   // 32 KB B-fragment chunk
    __shared__ float red[256];
    __shared__ float rmx[4], rmn[4];

    const float* km = ws + KM_OFF + bh * SL;
    const float* qm = ws + QM_OFF + bh * SL + qt * 64;
    float c = ws[C_OFF];

    // load Km; block max/min (logits monotone in Km -> exact max subtraction)
    float lmax = -1e30f, lmin = 1e30f;
    #pragma unroll
    for (int i = 0; i < 4; i++) {
        float v = km[tid + 256 * i];
        kml[tid + 256 * i] = v;
        lmax = fmaxf(lmax, v); lmin = fminf(lmin, v);
    }
    #pragma unroll
    for (int m = 32; m; m >>= 1) {
        lmax = fmaxf(lmax, __shfl_xor(lmax, m));
        lmin = fminf(lmin, __shfl_xor(lmin, m));
    }
    if ((tid & 63) == 0) { rmx[tid >> 6] = lmax; rmn[tid >> 6] = lmin; }
    __syncthreads();
    float kmax = fmaxf(fmaxf(rmx[0], rmx[1]), fmaxf(rmx[2], rmx[3]));
    float kmin = fminf(fminf(rmn[0], rmn[1]), fminf(rmn[2], rmn[3]));
    if (tid < 64) {
        float a = c * qm[tid];
        aq[tid] = a;
        mq[tid] = (a > 0.f) ? a * kmax : a * kmin;
    }
    __syncthreads();
    // denominators: 4 threads per q row, 256 k each
    {
        int q = tid >> 2, g = tid & 3;
        float a = aq[q], m = mq[q];
        float s = 0.f;
        const float* kp = kml + g * 256;
        for (int k = 0; k < 256; k++) s += __expf(a * kp[k] - m);
        red[tid] = s;
        __syncthreads();
        if (tid < 64) {
            float d = red[tid * 4] + red[tid * 4 + 1] + red[tid * 4 + 2] + red[tid * 4 + 3];
            rq[tid] = 1.f / d;
        }
        __syncthreads();
    }

    int w = tid >> 6, lane = tid & 63;
    int m16 = lane & 15, kg = lane >> 4;
    int qloc = w * 16 + m16;                      // this lane's q row (A-frag m)
    float a = aq[qloc], mm = mq[qloc], rr = rq[qloc];
    float* attn_row = out + 4194304 + ((size_t)(bh * SL + qt * 64 + qloc)) * SL;
    const uint4* vt4 = (const uint4*)((const unsigned short*)(ws + VT_OFF) + (size_t)bh * 4 * 16384);

    f32x4 acc0 = {0,0,0,0}, acc1 = {0,0,0,0}, acc2 = {0,0,0,0}, acc3 = {0,0,0,0};

    for (int ch = 0; ch < 4; ch++) {
        // stage 32 KB of packed V-fragments (linear, conflict-free)
        const uint4* src = vt4 + ch * 2048;
        uint4* dst = (uint4*)bpk;
        #pragma unroll
        for (int i = 0; i < 8; i++) dst[tid + 256 * i] = src[tid + 256 * i];
        __syncthreads();

        #pragma unroll
        for (int s = 0; s < 8; s++) {
            int k0 = ch * 256 + s * 32 + kg * 8;
            const float* kp = kml + k0;
            float e[8];
            #pragma unroll
            for (int j = 0; j < 8; j++) e[j] = __expf(a * kp[j] - mm) * rr;
            // write attn (fp32, exact): 2x float4, 16B/lane
            *(float4*)(attn_row + k0)     = make_float4(e[0], e[1], e[2], e[3]);
            *(float4*)(attn_row + k0 + 4) = make_float4(e[4], e[5], e[6], e[7]);
            // A fragment in bf16 (lane computes exactly its own fragment)
            unsigned short af[8];
            #pragma unroll
            for (int j = 0; j < 8; j++) af[j] = f2bf(e[j]);
            short8 av = *(short8*)af;
            const short8* bbase = (const short8*)bpk + s * 64 + lane;
            short8 b0 = bbase[0 * 512];
            short8 b1 = bbase[1 * 512];
            short8 b2 = bbase[2 * 512];
            short8 b3 = bbase[3 * 512];
            acc0 = __builtin_amdgcn_mfma_f32_16x16x32_bf16(av, b0, acc0, 0, 0, 0);
            acc1 = __builtin_amdgcn_mfma_f32_16x16x32_bf16(av, b1, acc1, 0, 0, 0);
            acc2 = __builtin_amdgcn_mfma_f32_16x16x32_bf16(av, b2, acc2, 0, 0, 0);
            acc3 = __builtin_amdgcn_mfma_f32_16x16x32_bf16(av, b3, acc3, 0, 0, 0);
        }
        __syncthreads();
    }
    // epilogue: C layout col=lane&15 (d), row=(lane>>4)*4+reg (q)
    float* ctx = out + ((size_t)(bh * SL + qt * 64 + w * 16)) * 64;
    #pragma unroll
    for (int reg = 0; reg < 4; reg++) {
        int row = kg * 4 + reg;
        float* cp = ctx + row * 64 + m16;
        cp[0]  = acc0[reg];
        cp[16] = acc1[reg];
        cp[32] = acc2[reg];
        cp[48] = acc3[reg];
    }
}

extern "C" void kernel_launch(void* const* d_in, const int* in_sizes, int n_in,
                              void* d_out, int out_size, void* d_ws, size_t ws_size,
                              hipStream_t stream)
{
    const float* Q      = (const float*)d_in[0];
    const float* K      = (const float*)d_in[1];
    const float* V      = (const float*)d_in[2];
    const float* wq     = (const float*)d_in[4];
    const float* wk     = (const float*)d_in[5];
    const float* wbq    = (const float*)d_in[6];
    const float* wbk    = (const float*)d_in[7];
    const float* cq3_w  = (const float*)d_in[8];
    const float* cq3_b  = (const float*)d_in[9];
    const float* cq9_w  = (const float*)d_in[10];
    const float* cq9_b  = (const float*)d_in[11];
    const float* ck3_w  = (const float*)d_in[12];
    const float* ck3_b  = (const float*)d_in[13];
    const float* ck9_w  = (const float*)d_in[14];
    const float* ck9_b  = (const float*)d_in[15];
    const float* bnq3_g = (const float*)d_in[16];
    const float* bnq3_b = (const float*)d_in[17];
    const float* bnq9_g = (const float*)d_in[18];
    const float* bnq9_b = (const float*)d_in[19];
    const float* bnk3_g = (const float*)d_in[20];
    const float* bnk3_b = (const float*)d_in[21];
    const float* bnk9_g = (const float*)d_in[22];
    const float* bnk9_b = (const float*)d_in[23];
    float* out = (float*)d_out;
    float* ws  = (float*)d_ws;

    (void)hipMemsetAsync(ws + ST_OFF, 0, 64 * sizeof(float), stream);

    k_projpack<<<10241, 256, 0, stream>>>(Q, K, V, wq, wk, wbq, wbk, ws);
    k_conv<<<256, 256, 0, stream>>>(ws, cq3_w, cq3_b, cq9_w, cq9_b,
                                    ck3_w, ck3_b, ck9_w, ck9_b);
    k_bnmix<<<128, 256, 0, stream>>>(ws, bnq3_g, bnq3_b, bnq9_g, bnq9_b,
                                     bnk3_g, bnk3_b, bnk9_g, bnk9_b);
    k_attn<<<1024, 256, 0, stream>>>(out, ws);
}